// Round 2
// baseline (176.690 us; speedup 1.0000x reference)
//
#include <hip/hip_runtime.h>

#define SCALE 0.17677669529663687f  // 1/sqrt(32)

// ---------------------------------------------------------------------------
// Kernel A: per-row projections. 256 blocks x 256 thr, 2 rows/block.
// q_ws (fp32, pre-scaled, [i][nd]), kT_ws (fp32, [nd][j]), v_ws (fp32, [j][nd]),
// qW_ws (fp32, [i][c*8+n]) where qW = sum_d q_scaled[i][n*32+d]*We[c][n*32+d]
// ---------------------------------------------------------------------------
__global__ __launch_bounds__(256) void proj_kernel(
    const float* __restrict__ x, const float* __restrict__ Wq,
    const float* __restrict__ Wk, const float* __restrict__ Wv,
    const float* __restrict__ We,
    float* __restrict__ q_ws, float* __restrict__ qW_ws,
    float* __restrict__ kT_ws, float* __restrict__ v_ws) {
  const int t = threadIdx.x;
  const int i0 = blockIdx.x * 2;
  __shared__ float s_x[2][64];
  __shared__ float s_q[2][256];
  if (t < 128) s_x[t >> 6][t & 63] = x[(i0 + (t >> 6)) * 64 + (t & 63)];
  __syncthreads();
  float aq0 = 0, aq1 = 0, ak0 = 0, ak1 = 0, av0 = 0, av1 = 0;
#pragma unroll 8
  for (int c = 0; c < 64; ++c) {
    float wq = Wq[c * 256 + t];
    float wk = Wk[c * 256 + t];
    float wv = Wv[c * 256 + t];
    float x0 = s_x[0][c], x1 = s_x[1][c];
    aq0 += x0 * wq; aq1 += x1 * wq;
    ak0 += x0 * wk; ak1 += x1 * wk;
    av0 += x0 * wv; av1 += x1 * wv;
  }
  q_ws[i0 * 256 + t] = aq0 * SCALE;
  q_ws[(i0 + 1) * 256 + t] = aq1 * SCALE;
  s_q[0][t] = aq0 * SCALE;
  s_q[1][t] = aq1 * SCALE;
  kT_ws[t * 512 + i0] = ak0;
  kT_ws[t * 512 + i0 + 1] = ak1;
  v_ws[i0 * 256 + t] = av0;
  v_ws[(i0 + 1) * 256 + t] = av1;
  __syncthreads();
#pragma unroll
  for (int it = 0; it < 4; ++it) {
    int idx2 = t + it * 256;       // 0..1023
    int r = idx2 >> 9;             // row within the pair
    int rem = idx2 & 511;          // c*8+n
    int c = rem >> 3, n = rem & 7;
    float a = 0;
#pragma unroll
    for (int d = 0; d < 32; ++d) a += s_q[r][n * 32 + d] * We[c * 256 + n * 32 + d];
    qW_ws[(i0 + r) * 512 + rem] = a;
  }
}

// ---------------------------------------------------------------------------
// Kernel B: qk[i][n][j] = q_scaled[i,:] . k[j,:] per head.
// 512 blocks (128 i-tiles x 4 j-quarters) x 256 thr.
// ---------------------------------------------------------------------------
__global__ __launch_bounds__(256) void qk_kernel(
    const float* __restrict__ q_ws, const float* __restrict__ kT_ws,
    float* __restrict__ qk_ws) {
  const int t = threadIdx.x;
  const int it = blockIdx.x & 127, js = blockIdx.x >> 7;
  const int i0 = it * 4, j0 = js * 128;
  __shared__ float s_qs[4][256];
#pragma unroll
  for (int u = 0; u < 4; ++u) {
    int idx = t + u * 256;
    s_qs[idx >> 8][idx & 255] = q_ws[(i0 + (idx >> 8)) * 256 + (idx & 255)];
  }
  __syncthreads();
  const int jrel = t & 63, nb = t >> 6;   // nb in 0..3, heads nb and nb+4
  float acc[2][4][2];
#pragma unroll
  for (int a = 0; a < 2; ++a)
#pragma unroll
    for (int b = 0; b < 4; ++b) { acc[a][b][0] = 0; acc[a][b][1] = 0; }
#pragma unroll
  for (int nn = 0; nn < 2; ++nn) {
    int n = nb + nn * 4;
    for (int d = 0; d < 32; ++d) {
      int nd = n * 32 + d;
      float k0 = kT_ws[nd * 512 + j0 + jrel];
      float k1 = kT_ws[nd * 512 + j0 + jrel + 64];
#pragma unroll
      for (int ii = 0; ii < 4; ++ii) {
        float qv = s_qs[ii][nd];
        acc[nn][ii][0] += qv * k0;
        acc[nn][ii][1] += qv * k1;
      }
    }
  }
#pragma unroll
  for (int nn = 0; nn < 2; ++nn)
#pragma unroll
    for (int ii = 0; ii < 4; ++ii) {
      int n = nb + nn * 4;
      qk_ws[(i0 + ii) * 4096 + n * 512 + j0 + jrel] = acc[nn][ii][0];
      qk_ws[(i0 + ii) * 4096 + n * 512 + j0 + jrel + 64] = acc[nn][ii][1];
    }
}

// ---------------------------------------------------------------------------
// Kernel C: fused per-query-row attention. 512 blocks (one per i) x 256 thr.
// logits[n][j] = qk[i,n,j] + sum_c e[i,j,c]*qW[i,c*8+n]   (q pre-scaled)
// out[i] = (sum_j p*v[j]  +  (sum_j p*e[i,j,:]) @ We) @ Wo + bo
// ---------------------------------------------------------------------------
__global__ __launch_bounds__(256) void attn_kernel(
    const float* __restrict__ e, const float* __restrict__ qW_ws,
    const float* __restrict__ qk_ws, const float* __restrict__ v_ws,
    const float* __restrict__ We, const float* __restrict__ Wo,
    const float* __restrict__ bo, float* __restrict__ out) {
  const int t = threadIdx.x;
  const int i = blockIdx.x;
  __shared__ __align__(16) float s_p[8 * 512];
  __shared__ float s_ae[512];
  __shared__ float s_emb[256];
  const int n = t >> 5, lane = t & 31;

  // ---- Phase 1: logits
  const float* qwr = qW_ws + i * 512;          // block-uniform -> scalar loads
#pragma unroll
  for (int jj = 0; jj < 2; ++jj) {
    const int j = t + jj * 256;
    float acc[8];
#pragma unroll
    for (int h = 0; h < 8; ++h) acc[h] = qk_ws[i * 4096 + h * 512 + j];
    const float4* erow = (const float4*)(e + (size_t)(i * 512 + j) * 64);
#pragma unroll
    for (int c4 = 0; c4 < 16; ++c4) {
      float4 E = erow[c4];
      float ev[4] = {E.x, E.y, E.z, E.w};
#pragma unroll
      for (int cc = 0; cc < 4; ++cc) {
        const float* qwc = qwr + (c4 * 4 + cc) * 8;
#pragma unroll
        for (int h = 0; h < 8; ++h) acc[h] += ev[cc] * qwc[h];
      }
    }
#pragma unroll
    for (int h = 0; h < 8; ++h) s_p[h * 512 + j] = acc[h];
  }
  __syncthreads();

  // ---- Phase 2: softmax per head (32 lanes per head), normalize p in place
  float m = -1e30f;
  for (int jj = lane; jj < 512; jj += 32) m = fmaxf(m, s_p[n * 512 + jj]);
#pragma unroll
  for (int off = 16; off; off >>= 1) m = fmaxf(m, __shfl_xor(m, off, 32));
  float sum = 0;
  for (int jj = lane; jj < 512; jj += 32) {
    float p = __expf(s_p[n * 512 + jj] - m);
    s_p[n * 512 + jj] = p;
    sum += p;
  }
#pragma unroll
  for (int off = 16; off; off >>= 1) sum += __shfl_xor(sum, off, 32);
  float inv = 1.0f / sum;
  for (int jj = lane; jj < 512; jj += 32) s_p[n * 512 + jj] *= inv;
  __syncthreads();

  // ---- Phase 3: accV = sum_j p*v[j, n*32+lane]; accE = sum_j p*e[i,j,2*lane{,+1}]
  float accV = 0, accE0 = 0, accE1 = 0;
  const float* ebase = e + (size_t)(i * 512) * 64 + 2 * lane;
  const float* vbase = v_ws + n * 32 + lane;
  for (int j4 = 0; j4 < 512; j4 += 4) {
    float4 pv = *(const float4*)&s_p[n * 512 + j4];
    float pa[4] = {pv.x, pv.y, pv.z, pv.w};
#pragma unroll
    for (int k = 0; k < 4; ++k) {
      int j = j4 + k;
      float2 ee2 = *(const float2*)(ebase + (size_t)j * 64);
      accE0 += pa[k] * ee2.x;
      accE1 += pa[k] * ee2.y;
      accV += pa[k] * vbase[j * 256];
    }
  }
  s_ae[n * 64 + 2 * lane] = accE0;
  s_ae[n * 64 + 2 * lane + 1] = accE1;
  s_emb[t] = accV;
  __syncthreads();

  // ---- Epilogue: emb[nd] = accV + sum_c ae[n,c]*We[c,nd]; out = emb @ Wo + bo
  float emb = s_emb[t];
#pragma unroll 8
  for (int c = 0; c < 64; ++c) emb += s_ae[n * 64 + c] * We[c * 256 + t];
  s_emb[t] = emb;   // own slot only: no race
  __syncthreads();
  if (t < 64) {
    float o = bo[t];
    for (int m2 = 0; m2 < 256; ++m2) o += s_emb[m2] * Wo[m2 * 64 + t];
    out[i * 64 + t] = o;
  }
}

extern "C" void kernel_launch(void* const* d_in, const int* in_sizes, int n_in,
                              void* d_out, int out_size, void* d_ws, size_t ws_size,
                              hipStream_t stream) {
  const float* x  = (const float*)d_in[0];
  const float* e  = (const float*)d_in[1];
  const float* Wq = (const float*)d_in[2];
  const float* Wk = (const float*)d_in[3];
  const float* Wv = (const float*)d_in[4];
  const float* We = (const float*)d_in[5];
  const float* Wo = (const float*)d_in[6];
  const float* bo = (const float*)d_in[7];
  float* out = (float*)d_out;

  // workspace layout (10.5 MB total, fp32)
  float* q_ws  = (float*)d_ws;                 // 131072 f (512x256, scaled)
  float* qW_ws = q_ws + 131072;                // 262144 f (512 x [c*8+n])
  float* qk_ws = qW_ws + 262144;               // 2097152 f (512 x 8 x 512)
  float* kT_ws = qk_ws + 2097152;              // 131072 f (256 x 512)
  float* v_ws  = kT_ws + 131072;               // 131072 f (512 x 256)

  hipLaunchKernelGGL(proj_kernel, dim3(256), dim3(256), 0, stream,
                     x, Wq, Wk, Wv, We, q_ws, qW_ws, kT_ws, v_ws);
  hipLaunchKernelGGL(qk_kernel, dim3(512), dim3(256), 0, stream,
                     q_ws, kT_ws, qk_ws);
  hipLaunchKernelGGL(attn_kernel, dim3(512), dim3(256), 0, stream,
                     e, qW_ws, qk_ws, v_ws, We, Wo, bo, out);
}